// Round 1
// baseline (4482.022 us; speedup 1.0000x reference)
//
#include <hip/hip_runtime.h>
#include <hip/hip_bf16.h>
#include <stdint.h>

// Problem constants: B=2, N=2048, D=1024, H=16, head dim s=64.
#define BB 2
#define NN 2048
#define DD 1024
#define HH 16
#define SS 64

// ---------------- helpers ----------------

__device__ __forceinline__ float bf2f(uint16_t u) {
    return __uint_as_float(((uint32_t)u) << 16);
}

__device__ __forceinline__ uint16_t f2bf(float f) {
    uint32_t u = __float_as_uint(f);
    uint32_t r = (u + 0x7FFFu + ((u >> 16) & 1u)) >> 16;  // RNE
    return (uint16_t)r;
}

__device__ __forceinline__ float ldf(const void* p, size_t i, int bf) {
    if (bf) return bf2f(((const uint16_t*)p)[i]);
    return ((const float*)p)[i];
}

// ---------------- dtype detector ----------------
// If buffers hold bf16, each dword = two bf16 of N(0,1) data; the LOW u16's
// exponent field lands in [100,140] essentially always. If buffers hold fp32,
// the low u16 is random mantissa bits -> exponent uniform -> in range ~16%.
__global__ void detect_dtype(const uint32_t* __restrict__ x, int* __restrict__ flag) {
    int cnt = 0;
    for (int i = threadIdx.x; i < 1024; i += 64) {
        uint32_t w = x[i];
        int e = (int)((w >> 7) & 0xFFu);  // exponent of low-half-as-bf16
        if (e >= 100 && e <= 140) cnt++;
    }
    #pragma unroll
    for (int off = 32; off >= 1; off >>= 1) cnt += __shfl_xor(cnt, off);
    if (threadIdx.x == 0) *flag = (cnt > 600) ? 1 : 0;
}

// ---------------- QKV projection GEMM ----------------
// C[M=4096, N=3072] = X[4096,1024] @ Wqkv[3072,1024]^T + bqkv, then
// scatter to Q/K/V fp32 [B,H,N,64] with Q scaled by 1/8.
__global__ __launch_bounds__(256) void gemm_qkv(
    const void* __restrict__ X, const void* __restrict__ W,
    const void* __restrict__ bias, const int* __restrict__ flag,
    float* __restrict__ Qo, float* __restrict__ Ko, float* __restrict__ Vo)
{
    const int bf = *flag;
    __shared__ float As[32][68];
    __shared__ float Ws[32][68];
    const int t = threadIdx.x;
    const int m0 = blockIdx.y * 64;
    const int n0 = blockIdx.x * 64;
    const int ty = t >> 4, tx = t & 15;
    float c[4][4] = {};

    for (int k0 = 0; k0 < 1024; k0 += 32) {
        __syncthreads();
        if (bf) {
            const uint16_t* Xa = (const uint16_t*)X;
            const uint16_t* Wa = (const uint16_t*)W;
            #pragma unroll
            for (int i = 0; i < 8; ++i) {
                int f = t + i * 256;
                int r = f >> 5, kk = f & 31;
                As[kk][r] = bf2f(Xa[(size_t)(m0 + r) * 1024 + k0 + kk]);
                Ws[kk][r] = bf2f(Wa[(size_t)(n0 + r) * 1024 + k0 + kk]);
            }
        } else {
            const float* Xa = (const float*)X;
            const float* Wa = (const float*)W;
            #pragma unroll
            for (int i = 0; i < 8; ++i) {
                int f = t + i * 256;
                int r = f >> 5, kk = f & 31;
                As[kk][r] = Xa[(size_t)(m0 + r) * 1024 + k0 + kk];
                Ws[kk][r] = Wa[(size_t)(n0 + r) * 1024 + k0 + kk];
            }
        }
        __syncthreads();
        #pragma unroll
        for (int kk = 0; kk < 32; ++kk) {
            float4 av = *(const float4*)&As[kk][ty * 4];
            float4 wv = *(const float4*)&Ws[kk][tx * 4];
            float a[4] = {av.x, av.y, av.z, av.w};
            float w[4] = {wv.x, wv.y, wv.z, wv.w};
            #pragma unroll
            for (int i = 0; i < 4; ++i)
                #pragma unroll
                for (int j = 0; j < 4; ++j)
                    c[i][j] += a[i] * w[j];
        }
    }

    #pragma unroll
    for (int i = 0; i < 4; ++i) {
        int m = m0 + ty * 4 + i;
        int b = m >> 11, row = m & 2047;
        #pragma unroll
        for (int j = 0; j < 4; ++j) {
            int n = n0 + tx * 4 + j;
            float v = c[i][j] + ldf(bias, n, bf);
            int part = n >> 10;
            int rr = n & 1023;
            int h = rr >> 6, dd = rr & 63;
            if (part == 0) v *= 0.125f;  // 1/sqrt(64)
            float* dst = (part == 0) ? Qo : ((part == 1) ? Ko : Vo);
            dst[(((size_t)(b * 16 + h)) * 2048 + row) * 64 + dd] = v;
        }
    }
}

// ---------------- causal attention ----------------
// One 64-lane wave per (b, h, query row). Lane j handles keys j, j+64, ...
// Online softmax per lane, then cross-lane merge via padded LDS transpose.
__global__ __launch_bounds__(64) void attn(
    const float* __restrict__ Q, const float* __restrict__ K,
    const float* __restrict__ V, float* __restrict__ Y)
{
    const int bid = blockIdx.x;
    const int bh = bid >> 11;     // 0..31
    const int row = bid & 2047;
    const int lane = threadIdx.x;

    const float4* q4 = (const float4*)(Q + (((size_t)bh * 2048) + row) * 64);
    const float4* K4 = (const float4*)(K + (size_t)bh * 2048 * 64);
    const float4* V4 = (const float4*)(V + (size_t)bh * 2048 * 64);

    __shared__ float red[64 * 33];

    float4 qreg[16];
    #pragma unroll
    for (int dd = 0; dd < 16; ++dd) qreg[dd] = q4[dd];

    float mx = -INFINITY, l = 0.f;
    float acc[64];
    #pragma unroll
    for (int d = 0; d < 64; ++d) acc[d] = 0.f;

    for (int j = lane; j <= row; j += 64) {
        const float4* Kr = K4 + (size_t)j * 16;
        float s = 0.f;
        #pragma unroll
        for (int dd = 0; dd < 16; ++dd) {
            float4 kv = Kr[dd];
            s += qreg[dd].x * kv.x + qreg[dd].y * kv.y +
                 qreg[dd].z * kv.z + qreg[dd].w * kv.w;
        }
        float mn = fmaxf(mx, s);
        float sc = __expf(mx - mn);   // 0 on first iteration (mx = -inf)
        float p  = __expf(s - mn);
        l = l * sc + p;
        const float4* Vr = V4 + (size_t)j * 16;
        #pragma unroll
        for (int dd = 0; dd < 16; ++dd) {
            float4 vv = Vr[dd];
            acc[dd * 4 + 0] = acc[dd * 4 + 0] * sc + p * vv.x;
            acc[dd * 4 + 1] = acc[dd * 4 + 1] * sc + p * vv.y;
            acc[dd * 4 + 2] = acc[dd * 4 + 2] * sc + p * vv.z;
            acc[dd * 4 + 3] = acc[dd * 4 + 3] * sc + p * vv.w;
        }
        mx = mn;
    }

    // global max / sum across lanes
    float gm = mx;
    #pragma unroll
    for (int off = 32; off >= 1; off >>= 1) gm = fmaxf(gm, __shfl_xor(gm, off));
    float w = __expf(mx - gm);        // 0 for lanes with no keys
    float lw = l * w;
    #pragma unroll
    for (int off = 32; off >= 1; off >>= 1) lw += __shfl_xor(lw, off);
    float inv = 1.0f / lw;

    const int b = bh >> 4, h = bh & 15;
    float* yrow = Y + ((((size_t)b * 2048 + row) * 16) + h) * 64;

    #pragma unroll
    for (int cc = 0; cc < 2; ++cc) {
        __syncthreads();
        #pragma unroll
        for (int d = 0; d < 32; ++d) red[lane * 33 + d] = acc[cc * 32 + d] * w;
        __syncthreads();
        int dcol = lane & 31;
        int j0 = (lane >> 5) * 32;
        float part = 0.f;
        #pragma unroll
        for (int i = 0; i < 32; ++i) part += red[(j0 + i) * 33 + dcol];
        part += __shfl_xor(part, 32);
        if (lane < 32) yrow[cc * 32 + dcol] = part * inv;
    }
}

// ---------------- output projection GEMM ----------------
// out[M=4096, N=1024] = Y[4096,1024] @ Wo[1024,1024]^T + bo
__global__ __launch_bounds__(256) void gemm_proj(
    const float* __restrict__ Yin, const void* __restrict__ W,
    const void* __restrict__ bias, const int* __restrict__ flag,
    void* __restrict__ out)
{
    const int bf = *flag;
    __shared__ float As[32][68];
    __shared__ float Ws[32][68];
    const int t = threadIdx.x;
    const int m0 = blockIdx.y * 64;
    const int n0 = blockIdx.x * 64;
    const int ty = t >> 4, tx = t & 15;
    float c[4][4] = {};

    for (int k0 = 0; k0 < 1024; k0 += 32) {
        __syncthreads();
        if (bf) {
            const uint16_t* Wa = (const uint16_t*)W;
            #pragma unroll
            for (int i = 0; i < 8; ++i) {
                int f = t + i * 256;
                int r = f >> 5, kk = f & 31;
                As[kk][r] = Yin[(size_t)(m0 + r) * 1024 + k0 + kk];
                Ws[kk][r] = bf2f(Wa[(size_t)(n0 + r) * 1024 + k0 + kk]);
            }
        } else {
            const float* Wa = (const float*)W;
            #pragma unroll
            for (int i = 0; i < 8; ++i) {
                int f = t + i * 256;
                int r = f >> 5, kk = f & 31;
                As[kk][r] = Yin[(size_t)(m0 + r) * 1024 + k0 + kk];
                Ws[kk][r] = Wa[(size_t)(n0 + r) * 1024 + k0 + kk];
            }
        }
        __syncthreads();
        #pragma unroll
        for (int kk = 0; kk < 32; ++kk) {
            float4 av = *(const float4*)&As[kk][ty * 4];
            float4 wv = *(const float4*)&Ws[kk][tx * 4];
            float a[4] = {av.x, av.y, av.z, av.w};
            float w[4] = {wv.x, wv.y, wv.z, wv.w};
            #pragma unroll
            for (int i = 0; i < 4; ++i)
                #pragma unroll
                for (int j = 0; j < 4; ++j)
                    c[i][j] += a[i] * w[j];
        }
    }

    #pragma unroll
    for (int i = 0; i < 4; ++i) {
        int m = m0 + ty * 4 + i;
        #pragma unroll
        for (int j = 0; j < 4; ++j) {
            int n = n0 + tx * 4 + j;
            float v = c[i][j] + ldf(bias, n, bf);
            size_t idx = (size_t)m * 1024 + n;
            if (bf) ((uint16_t*)out)[idx] = f2bf(v);
            else    ((float*)out)[idx] = v;
        }
    }
}

// ---------------- launcher ----------------

extern "C" void kernel_launch(void* const* d_in, const int* in_sizes, int n_in,
                              void* d_out, int out_size, void* d_ws, size_t ws_size,
                              hipStream_t stream) {
    const void* x    = d_in[0];
    // d_in[1] is the causal mask: deterministic triu(ones,k=1) -> applied structurally.
    const void* Wqkv = d_in[2];
    const void* bqkv = d_in[3];
    const void* Wo   = d_in[4];
    const void* bo   = d_in[5];

    int*   flag = (int*)d_ws;
    float* wsf  = (float*)d_ws;
    const size_t SZ = (size_t)BB * HH * NN * SS;  // 4,194,304
    float* Qw = wsf + 64;
    float* Kw = Qw + SZ;
    float* Vw = Kw + SZ;
    float* Yw = Vw + SZ;

    detect_dtype<<<1, 64, 0, stream>>>((const uint32_t*)x, flag);
    gemm_qkv<<<dim3(48, 64), 256, 0, stream>>>(x, Wqkv, bqkv, flag, Qw, Kw, Vw);
    attn<<<BB * HH * NN, 64, 0, stream>>>(Qw, Kw, Vw, Yw);
    gemm_proj<<<dim3(16, 64), 256, 0, stream>>>(Yw, Wo, bo, flag, d_out);
}

// Round 2
// 678.756 us; speedup vs baseline: 6.6033x; 6.6033x over previous
//
#include <hip/hip_runtime.h>
#include <hip/hip_bf16.h>
#include <stdint.h>

// Problem constants: B=2, N=2048, D=1024, H=16, head dim s=64.
#define BB 2
#define NN 2048
#define DD 1024
#define HH 16
#define SS 64

typedef short short8 __attribute__((ext_vector_type(8)));
typedef float f32x4 __attribute__((ext_vector_type(4)));

// ---------------- helpers ----------------

__device__ __forceinline__ float bf2f(uint16_t u) {
    return __uint_as_float(((uint32_t)u) << 16);
}

__device__ __forceinline__ uint16_t f2bf(float f) {
    uint32_t u = __float_as_uint(f);
    uint32_t r = (u + 0x7FFFu + ((u >> 16) & 1u)) >> 16;  // RNE
    return (uint16_t)r;
}

__device__ __forceinline__ float ldf(const void* p, size_t i, int bf) {
    if (bf) return bf2f(((const uint16_t*)p)[i]);
    return ((const float*)p)[i];
}

// ---------------- dtype detector ----------------
__global__ void detect_dtype(const uint32_t* __restrict__ x, int* __restrict__ flag) {
    int cnt = 0;
    for (int i = threadIdx.x; i < 1024; i += 64) {
        uint32_t w = x[i];
        int e = (int)((w >> 7) & 0xFFu);
        if (e >= 100 && e <= 140) cnt++;
    }
    #pragma unroll
    for (int off = 32; off >= 1; off >>= 1) cnt += __shfl_xor(cnt, off);
    if (threadIdx.x == 0) *flag = (cnt > 600) ? 1 : 0;
}

// ---------------- QKV projection GEMM ----------------
// C[4096,3072] = X @ Wqkv^T + bqkv -> bf16 Q (x0.125), bf16 K  [bh][2048][64],
// bf16 V^T [bh][64][2048].
__global__ __launch_bounds__(256) void gemm_qkv(
    const void* __restrict__ X, const void* __restrict__ W,
    const void* __restrict__ bias, const int* __restrict__ flag,
    uint16_t* __restrict__ Qb, uint16_t* __restrict__ Kb, uint16_t* __restrict__ Vt)
{
    const int bf = *flag;
    __shared__ float As[32][68];
    __shared__ float Ws[32][68];
    const int t = threadIdx.x;
    const int m0 = blockIdx.y * 64;
    const int n0 = blockIdx.x * 64;
    const int ty = t >> 4, tx = t & 15;
    float c[4][4] = {};

    for (int k0 = 0; k0 < 1024; k0 += 32) {
        __syncthreads();
        if (bf) {
            const uint16_t* Xa = (const uint16_t*)X;
            const uint16_t* Wa = (const uint16_t*)W;
            #pragma unroll
            for (int i = 0; i < 8; ++i) {
                int f = t + i * 256;
                int r = f >> 5, kk = f & 31;
                As[kk][r] = bf2f(Xa[(size_t)(m0 + r) * 1024 + k0 + kk]);
                Ws[kk][r] = bf2f(Wa[(size_t)(n0 + r) * 1024 + k0 + kk]);
            }
        } else {
            const float* Xa = (const float*)X;
            const float* Wa = (const float*)W;
            #pragma unroll
            for (int i = 0; i < 8; ++i) {
                int f = t + i * 256;
                int r = f >> 5, kk = f & 31;
                As[kk][r] = Xa[(size_t)(m0 + r) * 1024 + k0 + kk];
                Ws[kk][r] = Wa[(size_t)(n0 + r) * 1024 + k0 + kk];
            }
        }
        __syncthreads();
        #pragma unroll
        for (int kk = 0; kk < 32; ++kk) {
            float4 av = *(const float4*)&As[kk][ty * 4];
            float4 wv = *(const float4*)&Ws[kk][tx * 4];
            float a[4] = {av.x, av.y, av.z, av.w};
            float w[4] = {wv.x, wv.y, wv.z, wv.w};
            #pragma unroll
            for (int i = 0; i < 4; ++i)
                #pragma unroll
                for (int j = 0; j < 4; ++j)
                    c[i][j] += a[i] * w[j];
        }
    }

    // epilogue: block-uniform part / head
    const int n_part = n0 >> 10;                      // 0=Q 1=K 2=V
    const int hh = (n0 & 1023) >> 6;                  // head (uniform: 64 | 1024 tiling)
    const int bh = ((m0 >> 11) << 4) + hh;            // b*16 + h

    float vv[4][4];
    #pragma unroll
    for (int i = 0; i < 4; ++i)
        #pragma unroll
        for (int j = 0; j < 4; ++j)
            vv[i][j] = c[i][j] + ldf(bias, n0 + tx * 4 + j, bf);

    if (n_part < 2) {
        uint16_t* dst = (n_part == 0) ? Qb : Kb;
        const float scl = (n_part == 0) ? 0.125f : 1.0f;
        #pragma unroll
        for (int i = 0; i < 4; ++i) {
            int row = (m0 + ty * 4 + i) & 2047;
            ushort4 o;
            o.x = f2bf(vv[i][0] * scl);
            o.y = f2bf(vv[i][1] * scl);
            o.z = f2bf(vv[i][2] * scl);
            o.w = f2bf(vv[i][3] * scl);
            *(ushort4*)(dst + ((size_t)bh * 2048 + row) * 64 + tx * 4) = o;
        }
    } else {
        const int row0 = (m0 + ty * 4) & 2047;
        #pragma unroll
        for (int j = 0; j < 4; ++j) {
            int dd = tx * 4 + j;
            ushort4 o;
            o.x = f2bf(vv[0][j]);
            o.y = f2bf(vv[1][j]);
            o.z = f2bf(vv[2][j]);
            o.w = f2bf(vv[3][j]);
            *(ushort4*)(Vt + ((size_t)bh * 64 + dd) * 2048 + row0) = o;
        }
    }
}

// ---------------- MFMA flash attention ----------------
// Block = 4 waves; wave w owns 16 q-rows. Each block handles q-tiles
// {x, 31-x} -> uniform 33 kv-tile iterations. KV tile = 64 keys.
// All P re-layout through wave-private padded LDS (no barriers).
__global__ __launch_bounds__(256) void attn_mfma(
    const uint16_t* __restrict__ Q, const uint16_t* __restrict__ K,
    const uint16_t* __restrict__ Vt, uint16_t* __restrict__ Y)
{
    const int bh = blockIdx.y;
    const int w = threadIdx.x >> 6;
    const int lane = threadIdx.x & 63;
    const int lq = lane & 15;   // frag col (q-row for A, key/dim col for B/C)
    const int lg = lane >> 4;   // k-quarter / row-group

    __shared__ __align__(16) uint16_t Pl[4][16][72];  // per-wave, stride 144B

    const uint16_t* Kb = K + (size_t)bh * (2048 * 64);
    const uint16_t* Vb = Vt + (size_t)bh * (64 * 2048);
    const int b = bh >> 4, h = bh & 15;

    for (int half = 0; half < 2; ++half) {
        const int qt = half ? (31 - (int)blockIdx.x) : (int)blockIdx.x;
        const int q0 = qt * 64 + w * 16;

        const uint16_t* qbase = Q + ((size_t)bh * 2048 + q0 + lq) * 64 + lg * 8;
        short8 qf0 = *(const short8*)qbase;
        short8 qf1 = *(const short8*)(qbase + 32);

        f32x4 y[4] = {};
        float m[4], lsum[4];
        #pragma unroll
        for (int r = 0; r < 4; ++r) { m[r] = -INFINITY; lsum[r] = 0.f; }

        for (int kt = 0; kt <= qt; ++kt) {
            const int kv0 = kt * 64;
            // ---- S = Q K^T : 4 col-chunks x 2 k-chunks ----
            f32x4 s[4];
            #pragma unroll
            for (int n = 0; n < 4; ++n) {
                const uint16_t* kbase = Kb + (size_t)(kv0 + n * 16 + lq) * 64 + lg * 8;
                short8 kf0 = *(const short8*)kbase;
                short8 kf1 = *(const short8*)(kbase + 32);
                f32x4 z = {};
                z = __builtin_amdgcn_mfma_f32_16x16x32_bf16(qf0, kf0, z, 0, 0, 0);
                s[n] = __builtin_amdgcn_mfma_f32_16x16x32_bf16(qf1, kf1, z, 0, 0, 0);
            }
            // ---- causal mask (diagonal tile only) ----
            if (kt == qt) {
                const int rowb = q0 + lg * 4;
                #pragma unroll
                for (int n = 0; n < 4; ++n) {
                    int col = kv0 + n * 16 + lq;
                    #pragma unroll
                    for (int r = 0; r < 4; ++r)
                        if (col > rowb + r) s[n][r] = -INFINITY;
                }
            }
            // ---- online softmax ----
            float mt[4];
            #pragma unroll
            for (int r = 0; r < 4; ++r)
                mt[r] = fmaxf(fmaxf(s[0][r], s[1][r]), fmaxf(s[2][r], s[3][r]));
            #pragma unroll
            for (int off = 1; off <= 8; off <<= 1)
                #pragma unroll
                for (int r = 0; r < 4; ++r)
                    mt[r] = fmaxf(mt[r], __shfl_xor(mt[r], off));
            float sc[4], psum[4];
            #pragma unroll
            for (int r = 0; r < 4; ++r) {
                float mn = fmaxf(m[r], mt[r]);
                sc[r] = __expf(m[r] - mn);
                m[r] = mn;
                psum[r] = 0.f;
            }
            #pragma unroll
            for (int n = 0; n < 4; ++n)
                #pragma unroll
                for (int r = 0; r < 4; ++r) {
                    float p = __expf(s[n][r] - m[r]);
                    psum[r] += p;
                    Pl[w][lg * 4 + r][n * 16 + lq] = f2bf(p);
                }
            #pragma unroll
            for (int off = 1; off <= 8; off <<= 1)
                #pragma unroll
                for (int r = 0; r < 4; ++r)
                    psum[r] += __shfl_xor(psum[r], off);
            #pragma unroll
            for (int r = 0; r < 4; ++r) lsum[r] = lsum[r] * sc[r] + psum[r];
            #pragma unroll
            for (int n = 0; n < 4; ++n)
                #pragma unroll
                for (int r = 0; r < 4; ++r)
                    y[n][r] *= sc[r];
            // ---- P fragments from LDS (wave-private, compiler inserts waits) ----
            short8 pa0 = *(short8*)&Pl[w][lq][lg * 8];
            short8 pa1 = *(short8*)&Pl[w][lq][lg * 8 + 32];
            // ---- Y += P V ----
            #pragma unroll
            for (int n = 0; n < 4; ++n) {
                const uint16_t* vbase = Vb + (size_t)(n * 16 + lq) * 2048 + kv0 + lg * 8;
                short8 vf0 = *(const short8*)vbase;
                short8 vf1 = *(const short8*)(vbase + 32);
                y[n] = __builtin_amdgcn_mfma_f32_16x16x32_bf16(pa0, vf0, y[n], 0, 0, 0);
                y[n] = __builtin_amdgcn_mfma_f32_16x16x32_bf16(pa1, vf1, y[n], 0, 0, 0);
            }
        }
        // ---- epilogue: Y[token][h*64+d] bf16 ----
        #pragma unroll
        for (int r = 0; r < 4; ++r) {
            float inv = 1.0f / lsum[r];
            int token = b * 2048 + q0 + lg * 4 + r;
            uint16_t* yrow = Y + (size_t)token * 1024 + h * 64;
            #pragma unroll
            for (int n = 0; n < 4; ++n)
                yrow[n * 16 + lq] = f2bf(y[n][r] * inv);
        }
    }
}

// ---------------- output projection GEMM ----------------
// out[4096,1024] = Ybf16 @ Wo^T + bo
__global__ __launch_bounds__(256) void gemm_proj(
    const uint16_t* __restrict__ Yin, const void* __restrict__ W,
    const void* __restrict__ bias, const int* __restrict__ flag,
    void* __restrict__ out)
{
    const int bf = *flag;
    __shared__ float As[32][68];
    __shared__ float Ws[32][68];
    const int t = threadIdx.x;
    const int m0 = blockIdx.y * 64;
    const int n0 = blockIdx.x * 64;
    const int ty = t >> 4, tx = t & 15;
    float c[4][4] = {};

    for (int k0 = 0; k0 < 1024; k0 += 32) {
        __syncthreads();
        if (bf) {
            const uint16_t* Wa = (const uint16_t*)W;
            #pragma unroll
            for (int i = 0; i < 8; ++i) {
                int f = t + i * 256;
                int r = f >> 5, kk = f & 31;
                As[kk][r] = bf2f(Yin[(size_t)(m0 + r) * 1024 + k0 + kk]);
                Ws[kk][r] = bf2f(Wa[(size_t)(n0 + r) * 1024 + k0 + kk]);
            }
        } else {
            const float* Wa = (const float*)W;
            #pragma unroll
            for (int i = 0; i < 8; ++i) {
                int f = t + i * 256;
                int r = f >> 5, kk = f & 31;
                As[kk][r] = bf2f(Yin[(size_t)(m0 + r) * 1024 + k0 + kk]);
                Ws[kk][r] = Wa[(size_t)(n0 + r) * 1024 + k0 + kk];
            }
        }
        __syncthreads();
        #pragma unroll
        for (int kk = 0; kk < 32; ++kk) {
            float4 av = *(const float4*)&As[kk][ty * 4];
            float4 wv = *(const float4*)&Ws[kk][tx * 4];
            float a[4] = {av.x, av.y, av.z, av.w};
            float w[4] = {wv.x, wv.y, wv.z, wv.w};
            #pragma unroll
            for (int i = 0; i < 4; ++i)
                #pragma unroll
                for (int j = 0; j < 4; ++j)
                    c[i][j] += a[i] * w[j];
        }
    }

    #pragma unroll
    for (int i = 0; i < 4; ++i) {
        int mrow = m0 + ty * 4 + i;
        #pragma unroll
        for (int j = 0; j < 4; ++j) {
            int n = n0 + tx * 4 + j;
            float v = c[i][j] + ldf(bias, n, bf);
            size_t idx = (size_t)mrow * 1024 + n;
            if (bf) ((uint16_t*)out)[idx] = f2bf(v);
            else    ((float*)out)[idx] = v;
        }
    }
}

// ---------------- launcher ----------------

extern "C" void kernel_launch(void* const* d_in, const int* in_sizes, int n_in,
                              void* d_out, int out_size, void* d_ws, size_t ws_size,
                              hipStream_t stream) {
    const void* x    = d_in[0];
    // d_in[1] (causal mask) applied structurally.
    const void* Wqkv = d_in[2];
    const void* bqkv = d_in[3];
    const void* Wo   = d_in[4];
    const void* bo   = d_in[5];

    int* flag = (int*)d_ws;
    const size_t QK = (size_t)BB * HH * NN * SS;  // 4,194,304 elems
    uint16_t* Qb = (uint16_t*)((char*)d_ws + 256);
    uint16_t* Kb = Qb + QK;
    uint16_t* Vt = Kb + QK;
    uint16_t* Yb = Vt + QK;

    detect_dtype<<<1, 64, 0, stream>>>((const uint32_t*)x, flag);
    gemm_qkv<<<dim3(48, 64), 256, 0, stream>>>(x, Wqkv, bqkv, flag, Qb, Kb, Vt);
    attn_mfma<<<dim3(16, 32), 256, 0, stream>>>(Qb, Kb, Vt, Yb);
    gemm_proj<<<dim3(16, 64), 256, 0, stream>>>(Yb, Wo, bo, flag, d_out);
}

// Round 5
// 407.397 us; speedup vs baseline: 11.0016x; 1.6661x over previous
//
#include <hip/hip_runtime.h>
#include <hip/hip_bf16.h>
#include <stdint.h>

// Problem constants: B=2, N=2048, D=1024, H=16, head dim s=64.
// Global I/O is FP32 (verified: npz sizes + round-2 runtime-detector pass).
// Internal Q/K/V/Y intermediates are bf16 (own format).
#define BB 2
#define NN 2048
#define DD 1024
#define HH 16
#define SS 64

typedef short short8 __attribute__((ext_vector_type(8)));
typedef float f32x4 __attribute__((ext_vector_type(4)));

__device__ __forceinline__ float bf2f(uint16_t u) {
    return __uint_as_float(((uint32_t)u) << 16);
}
__device__ __forceinline__ uint16_t f2bf(float f) {
    uint32_t u = __float_as_uint(f);
    return (uint16_t)((u + 0x7FFFu + ((u >> 16) & 1u)) >> 16);  // RNE
}
__device__ __forceinline__ short8 cvt8(float4 a, float4 b) {
    short8 s;
    s[0] = (short)f2bf(a.x); s[1] = (short)f2bf(a.y);
    s[2] = (short)f2bf(a.z); s[3] = (short)f2bf(a.w);
    s[4] = (short)f2bf(b.x); s[5] = (short)f2bf(b.y);
    s[6] = (short)f2bf(b.z); s[7] = (short)f2bf(b.w);
    return s;
}

#define LDA_S 40   // padded LDS row stride (elements): 80B rows, 16B-aligned

// ======================= QKV projection (MFMA) =======================
// C[4096,3072] = X[4096,1024] @ Wqkv[3072,1024]^T + bqkv
// -> Q bf16 (x0.125) [bh][2048][64], K bf16 [bh][2048][64], V^T bf16 [bh][64][2048]
__global__ __launch_bounds__(256) void gemm_qkv(
    const float* __restrict__ X, const float* __restrict__ W,
    const float* __restrict__ bias,
    uint16_t* __restrict__ Qb, uint16_t* __restrict__ Kb, uint16_t* __restrict__ Vt)
{
    __shared__ __align__(16) uint16_t smem[18432];   // 36,864 B
    uint16_t* As = smem;            // [128][40] padded
    uint16_t* Bs = smem + 5120;     // [128][40]

    const int tid = threadIdx.x;
    const int w = tid >> 6, l = tid & 63;
    const int lq = l & 15, lg = l >> 4;
    const int wm = w >> 1, wn = w & 1;
    const int m0 = blockIdx.y * 128;
    const int n0 = blockIdx.x * 128;

    const int r0 = l >> 2;            // row within 16-row chunk
    const int c0 = (l & 3) * 8;       // column element offset
    const float* xa0 = X + (size_t)(m0 + w * 16 + r0) * 1024 + c0;
    const float* xa1 = xa0 + (size_t)64 * 1024;
    const float* wa0 = W + (size_t)(n0 + w * 16 + r0) * 1024 + c0;
    const float* wa1 = wa0 + (size_t)64 * 1024;
    uint16_t* la0 = As + (w * 16 + r0) * LDA_S + c0;
    uint16_t* la1 = la0 + 64 * LDA_S;
    uint16_t* lb0 = Bs + (w * 16 + r0) * LDA_S + c0;
    uint16_t* lb1 = lb0 + 64 * LDA_S;

    f32x4 acc[4][4] = {};

    float4 A00 = *(const float4*)xa0,       A01 = *(const float4*)(xa0 + 4);
    float4 A10 = *(const float4*)xa1,       A11 = *(const float4*)(xa1 + 4);
    float4 B00 = *(const float4*)wa0,       B01 = *(const float4*)(wa0 + 4);
    float4 B10 = *(const float4*)wa1,       B11 = *(const float4*)(wa1 + 4);

    for (int k0 = 0; k0 < 1024; k0 += 32) {
        __syncthreads();                 // prev-iter LDS reads complete
        *(short8*)la0 = cvt8(A00, A01);
        *(short8*)la1 = cvt8(A10, A11);
        *(short8*)lb0 = cvt8(B00, B01);
        *(short8*)lb1 = cvt8(B10, B11);
        __syncthreads();                 // tile visible to all waves

        const int kn = (k0 + 32 < 1024) ? (k0 + 32) : k0;   // clamped prefetch
        A00 = *(const float4*)(xa0 + kn); A01 = *(const float4*)(xa0 + kn + 4);
        A10 = *(const float4*)(xa1 + kn); A11 = *(const float4*)(xa1 + kn + 4);
        B00 = *(const float4*)(wa0 + kn); B01 = *(const float4*)(wa0 + kn + 4);
        B10 = *(const float4*)(wa1 + kn); B11 = *(const float4*)(wa1 + kn + 4);

        short8 af[4], bfr[4];
        #pragma unroll
        for (int mi = 0; mi < 4; ++mi)
            af[mi] = *(const short8*)&As[(wm * 64 + mi * 16 + lq) * LDA_S + lg * 8];
        #pragma unroll
        for (int ni = 0; ni < 4; ++ni)
            bfr[ni] = *(const short8*)&Bs[(wn * 64 + ni * 16 + lq) * LDA_S + lg * 8];
        #pragma unroll
        for (int mi = 0; mi < 4; ++mi)
            #pragma unroll
            for (int ni = 0; ni < 4; ++ni)
                acc[mi][ni] = __builtin_amdgcn_mfma_f32_16x16x32_bf16(
                    af[mi], bfr[ni], acc[mi][ni], 0, 0, 0);
    }

    // ---------------- epilogue: bf16 scatter via LDS transpose ----------------
    __syncthreads();  // staging reads complete; reuse smem
    const int part = n0 >> 10;                       // 0=Q 1=K 2=V (uniform)
    const int hh = ((n0 + wn * 64) & 1023) >> 6;     // head (uniform per wave)
    const int mrow0 = m0 + wm * 64;
    const int bh = (mrow0 >> 11) * 16 + hh;
    const int tok0 = mrow0 & 2047;
    const float scl = (part == 0) ? 0.125f : 1.0f;

    float bias4[4];
    #pragma unroll
    for (int ni = 0; ni < 4; ++ni)
        bias4[ni] = bias[n0 + wn * 64 + ni * 16 + lq];

    uint16_t* T = smem + w * 4608;                   // [64][72] bf16, wave-private
    if (part < 2) {
        #pragma unroll
        for (int mi = 0; mi < 4; ++mi)
            #pragma unroll
            for (int ni = 0; ni < 4; ++ni)
                #pragma unroll
                for (int r = 0; r < 4; ++r)
                    T[(mi * 16 + lg * 4 + r) * 72 + ni * 16 + lq] =
                        f2bf((acc[mi][ni][r] + bias4[ni]) * scl);
    } else {
        #pragma unroll
        for (int mi = 0; mi < 4; ++mi)
            #pragma unroll
            for (int ni = 0; ni < 4; ++ni)
                #pragma unroll
                for (int r = 0; r < 4; ++r)
                    T[(ni * 16 + lq) * 72 + mi * 16 + lg * 4 + r] =
                        f2bf(acc[mi][ni][r] + bias4[ni]);
    }

    const int a0 = l >> 3, b8 = (l & 7) * 8;
    #pragma unroll
    for (int i = 0; i < 8; ++i) {
        int a = i * 8 + a0;
        short8 u = *(short8*)&T[a * 72 + b8];
        uint16_t* p;
        if (part < 2) {
            uint16_t* dst = (part == 0) ? Qb : Kb;
            p = dst + ((size_t)bh * 2048 + tok0 + a) * 64 + b8;
        } else {
            p = Vt + ((size_t)bh * 64 + a) * 2048 + tok0 + b8;
        }
        *(short8*)p = u;
    }
}

// ======================= MFMA flash attention (round-2 verified) =======================
__global__ __launch_bounds__(256) void attn_mfma(
    const uint16_t* __restrict__ Q, const uint16_t* __restrict__ K,
    const uint16_t* __restrict__ Vt, uint16_t* __restrict__ Y)
{
    const int bh = blockIdx.y;
    const int w = threadIdx.x >> 6;
    const int lane = threadIdx.x & 63;
    const int lq = lane & 15;
    const int lg = lane >> 4;

    __shared__ __align__(16) uint16_t Pl[4][16][72];

    const uint16_t* Kb = K + (size_t)bh * (2048 * 64);
    const uint16_t* Vb = Vt + (size_t)bh * (64 * 2048);
    const int b = bh >> 4, h = bh & 15;

    for (int half = 0; half < 2; ++half) {
        const int qt = half ? (31 - (int)blockIdx.x) : (int)blockIdx.x;
        const int q0 = qt * 64 + w * 16;

        const uint16_t* qbase = Q + ((size_t)bh * 2048 + q0 + lq) * 64 + lg * 8;
        short8 qf0 = *(const short8*)qbase;
        short8 qf1 = *(const short8*)(qbase + 32);

        f32x4 y[4] = {};
        float m[4], lsum[4];
        #pragma unroll
        for (int r = 0; r < 4; ++r) { m[r] = -INFINITY; lsum[r] = 0.f; }

        for (int kt = 0; kt <= qt; ++kt) {
            const int kv0 = kt * 64;
            f32x4 s[4];
            #pragma unroll
            for (int n = 0; n < 4; ++n) {
                const uint16_t* kbase = Kb + (size_t)(kv0 + n * 16 + lq) * 64 + lg * 8;
                short8 kf0 = *(const short8*)kbase;
                short8 kf1 = *(const short8*)(kbase + 32);
                f32x4 z = {};
                z = __builtin_amdgcn_mfma_f32_16x16x32_bf16(qf0, kf0, z, 0, 0, 0);
                s[n] = __builtin_amdgcn_mfma_f32_16x16x32_bf16(qf1, kf1, z, 0, 0, 0);
            }
            if (kt == qt) {
                const int rowb = q0 + lg * 4;
                #pragma unroll
                for (int n = 0; n < 4; ++n) {
                    int col = kv0 + n * 16 + lq;
                    #pragma unroll
                    for (int r = 0; r < 4; ++r)
                        if (col > rowb + r) s[n][r] = -INFINITY;
                }
            }
            float mt[4];
            #pragma unroll
            for (int r = 0; r < 4; ++r)
                mt[r] = fmaxf(fmaxf(s[0][r], s[1][r]), fmaxf(s[2][r], s[3][r]));
            #pragma unroll
            for (int off = 1; off <= 8; off <<= 1)
                #pragma unroll
                for (int r = 0; r < 4; ++r)
                    mt[r] = fmaxf(mt[r], __shfl_xor(mt[r], off));
            float sc[4], psum[4];
            #pragma unroll
            for (int r = 0; r < 4; ++r) {
                float mn = fmaxf(m[r], mt[r]);
                sc[r] = __expf(m[r] - mn);
                m[r] = mn;
                psum[r] = 0.f;
            }
            #pragma unroll
            for (int n = 0; n < 4; ++n)
                #pragma unroll
                for (int r = 0; r < 4; ++r) {
                    float p = __expf(s[n][r] - m[r]);
                    psum[r] += p;
                    Pl[w][lg * 4 + r][n * 16 + lq] = f2bf(p);
                }
            #pragma unroll
            for (int off = 1; off <= 8; off <<= 1)
                #pragma unroll
                for (int r = 0; r < 4; ++r)
                    psum[r] += __shfl_xor(psum[r], off);
            #pragma unroll
            for (int r = 0; r < 4; ++r) lsum[r] = lsum[r] * sc[r] + psum[r];
            #pragma unroll
            for (int n = 0; n < 4; ++n)
                #pragma unroll
                for (int r = 0; r < 4; ++r)
                    y[n][r] *= sc[r];
            short8 pa0 = *(short8*)&Pl[w][lq][lg * 8];
            short8 pa1 = *(short8*)&Pl[w][lq][lg * 8 + 32];
            #pragma unroll
            for (int n = 0; n < 4; ++n) {
                const uint16_t* vbase = Vb + (size_t)(n * 16 + lq) * 2048 + kv0 + lg * 8;
                short8 vf0 = *(const short8*)vbase;
                short8 vf1 = *(const short8*)(vbase + 32);
                y[n] = __builtin_amdgcn_mfma_f32_16x16x32_bf16(pa0, vf0, y[n], 0, 0, 0);
                y[n] = __builtin_amdgcn_mfma_f32_16x16x32_bf16(pa1, vf1, y[n], 0, 0, 0);
            }
        }
        #pragma unroll
        for (int r = 0; r < 4; ++r) {
            float inv = 1.0f / lsum[r];
            int token = b * 2048 + q0 + lg * 4 + r;
            uint16_t* yrow = Y + (size_t)token * 1024 + h * 64;
            #pragma unroll
            for (int n = 0; n < 4; ++n)
                yrow[n * 16 + lq] = f2bf(y[n][r] * inv);
        }
    }
}

// ======================= output projection (MFMA, fp32 out) =======================
// out[4096,1024] = Y(bf16)[4096,1024] @ Wo(fp32)[1024,1024]^T + bo
__global__ __launch_bounds__(256) void gemm_proj(
    const uint16_t* __restrict__ Yin, const float* __restrict__ W,
    const float* __restrict__ bias, float* __restrict__ out)
{
    __shared__ __align__(16) uint16_t smem[10240];   // 2 x [128][40]
    uint16_t* As = smem;
    uint16_t* Bs = smem + 5120;

    const int tid = threadIdx.x;
    const int w = tid >> 6, l = tid & 63;
    const int lq = l & 15, lg = l >> 4;
    const int wm = w >> 1, wn = w & 1;
    const int m0 = blockIdx.y * 128;
    const int n0 = blockIdx.x * 128;

    const int r0 = l >> 2;
    const int c0 = (l & 3) * 8;
    const uint16_t* ya0 = Yin + (size_t)(m0 + w * 16 + r0) * 1024 + c0;
    const uint16_t* ya1 = ya0 + (size_t)64 * 1024;
    const float* wa0 = W + (size_t)(n0 + w * 16 + r0) * 1024 + c0;
    const float* wa1 = wa0 + (size_t)64 * 1024;
    uint16_t* la0 = As + (w * 16 + r0) * LDA_S + c0;
    uint16_t* la1 = la0 + 64 * LDA_S;
    uint16_t* lb0 = Bs + (w * 16 + r0) * LDA_S + c0;
    uint16_t* lb1 = lb0 + 64 * LDA_S;

    f32x4 acc[4][4] = {};

    short8 rA0 = *(const short8*)ya0;
    short8 rA1 = *(const short8*)ya1;
    float4 B00 = *(const float4*)wa0, B01 = *(const float4*)(wa0 + 4);
    float4 B10 = *(const float4*)wa1, B11 = *(const float4*)(wa1 + 4);

    for (int k0 = 0; k0 < 1024; k0 += 32) {
        __syncthreads();
        *(short8*)la0 = rA0;
        *(short8*)la1 = rA1;
        *(short8*)lb0 = cvt8(B00, B01);
        *(short8*)lb1 = cvt8(B10, B11);
        __syncthreads();

        const int kn = (k0 + 32 < 1024) ? (k0 + 32) : k0;
        rA0 = *(const short8*)(ya0 + kn);
        rA1 = *(const short8*)(ya1 + kn);
        B00 = *(const float4*)(wa0 + kn); B01 = *(const float4*)(wa0 + kn + 4);
        B10 = *(const float4*)(wa1 + kn); B11 = *(const float4*)(wa1 + kn + 4);

        short8 af[4], bfr[4];
        #pragma unroll
        for (int mi = 0; mi < 4; ++mi)
            af[mi] = *(const short8*)&As[(wm * 64 + mi * 16 + lq) * LDA_S + lg * 8];
        #pragma unroll
        for (int ni = 0; ni < 4; ++ni)
            bfr[ni] = *(const short8*)&Bs[(wn * 64 + ni * 16 + lq) * LDA_S + lg * 8];
        #pragma unroll
        for (int mi = 0; mi < 4; ++mi)
            #pragma unroll
            for (int ni = 0; ni < 4; ++ni)
                acc[mi][ni] = __builtin_amdgcn_mfma_f32_16x16x32_bf16(
                    af[mi], bfr[ni], acc[mi][ni], 0, 0, 0);
    }

    // epilogue: direct fp32 stores from C-fragment layout
    const int mrow0 = m0 + wm * 64;
    const int ncol0 = n0 + wn * 64;
    float bias4[4];
    #pragma unroll
    for (int ni = 0; ni < 4; ++ni)
        bias4[ni] = bias[ncol0 + ni * 16 + lq];

    #pragma unroll
    for (int mi = 0; mi < 4; ++mi)
        #pragma unroll
        for (int r = 0; r < 4; ++r) {
            const size_t rowoff = (size_t)(mrow0 + mi * 16 + lg * 4 + r) * 1024;
            #pragma unroll
            for (int ni = 0; ni < 4; ++ni)
                out[rowoff + ncol0 + ni * 16 + lq] = acc[mi][ni][r] + bias4[ni];
        }
}

// ======================= launcher =======================

extern "C" void kernel_launch(void* const* d_in, const int* in_sizes, int n_in,
                              void* d_out, int out_size, void* d_ws, size_t ws_size,
                              hipStream_t stream) {
    const float* x    = (const float*)d_in[0];
    // d_in[1] (causal mask) applied structurally.
    const float* Wqkv = (const float*)d_in[2];
    const float* bqkv = (const float*)d_in[3];
    const float* Wo   = (const float*)d_in[4];
    const float* bo   = (const float*)d_in[5];

    const size_t QK = (size_t)BB * HH * NN * SS;  // 4,194,304 elems
    uint16_t* Qb = (uint16_t*)((char*)d_ws + 256);
    uint16_t* Kb = Qb + QK;
    uint16_t* Vt = Kb + QK;
    uint16_t* Yb = Vt + QK;

    gemm_qkv<<<dim3(24, 32), 256, 0, stream>>>(x, Wqkv, bqkv, Qb, Kb, Vt);
    attn_mfma<<<dim3(16, 32), 256, 0, stream>>>(Qb, Kb, Vt, Yb);
    gemm_proj<<<dim3(8, 32), 256, 0, stream>>>(Yb, Wo, bo, (float*)d_out);
}

// Round 6
// 330.638 us; speedup vs baseline: 13.5557x; 1.2322x over previous
//
#include <hip/hip_runtime.h>
#include <hip/hip_bf16.h>
#include <stdint.h>

// Problem constants: B=2, N=2048, D=1024, H=16, head dim s=64.
// Global I/O fp32; internal X/W/Q/K/V/Y intermediates bf16 in d_ws.
#define BB 2
#define NN 2048
#define DD 1024
#define HH 16
#define SS 64

typedef short short8 __attribute__((ext_vector_type(8)));
typedef float f32x4 __attribute__((ext_vector_type(4)));

__device__ __forceinline__ float bf2f(uint16_t u) {
    return __uint_as_float(((uint32_t)u) << 16);
}
__device__ __forceinline__ uint16_t f2bf(float f) {
    uint32_t u = __float_as_uint(f);
    return (uint16_t)((u + 0x7FFFu + ((u >> 16) & 1u)) >> 16);  // RNE
}
__device__ __forceinline__ short8 cvt8(float4 a, float4 b) {
    short8 s;
    s[0] = (short)f2bf(a.x); s[1] = (short)f2bf(a.y);
    s[2] = (short)f2bf(a.z); s[3] = (short)f2bf(a.w);
    s[4] = (short)f2bf(b.x); s[5] = (short)f2bf(b.y);
    s[6] = (short)f2bf(b.z); s[7] = (short)f2bf(b.w);
    return s;
}

__device__ __forceinline__ void load_lds16(const uint16_t* g, uint16_t* l) {
    __builtin_amdgcn_global_load_lds(
        (const __attribute__((address_space(1))) void*)g,
        (__attribute__((address_space(3))) void*)l, 16, 0, 0);
}

// ======================= fp32 -> bf16 bulk convert =======================
__global__ __launch_bounds__(256) void cvt_bf16(
    const float* __restrict__ src, uint16_t* __restrict__ dst, int n)
{
    int i = (blockIdx.x * 256 + threadIdx.x) * 8;
    if (i >= n) return;
    float4 a = *(const float4*)(src + i);
    float4 b = *(const float4*)(src + i + 4);
    *(short8*)(dst + i) = cvt8(a, b);
}

// ======================= QKV projection (MFMA, bf16 in) =======================
// C[4096,3072] = X[4096,1024] @ Wqkv[3072,1024]^T + bqkv
// -> Q bf16 (x0.125) [bh][2048][64], K bf16 [bh][2048][64], V^T bf16 [bh][64][2048]
// m97 structure: 128x128 tile, BK=32, 4 waves x (64x64), global_load_lds w=16.
__global__ __launch_bounds__(256) void gemm_qkv(
    const uint16_t* __restrict__ X, const uint16_t* __restrict__ W,
    const float* __restrict__ bias,
    uint16_t* __restrict__ Qb, uint16_t* __restrict__ Kb, uint16_t* __restrict__ Vt)
{
    __shared__ __align__(16) uint16_t smem[18432];   // 36,864 B
    uint16_t* As = smem;          // [128][32] linear (gload_lds requires)
    uint16_t* Bs = smem + 4096;   // [128][32]

    const int tid = threadIdx.x;
    const int w = tid >> 6, l = tid & 63;
    const int lq = l & 15, lg = l >> 4;
    const int wm = w >> 1, wn = w & 1;
    const int m0 = blockIdx.y * 128;
    const int n0 = blockIdx.x * 128;

    f32x4 acc[4][4] = {};

    for (int k0 = 0; k0 < 1024; k0 += 32) {
        __syncthreads();
        #pragma unroll
        for (int j = 0; j < 2; ++j) {
            const int c = (j * 4 + w) * 64 + l;   // lane's global row/col chunk
            load_lds16(X + (size_t)(m0 + (c >> 2)) * 1024 + k0 + (c & 3) * 8,
                       As + (j * 4 + w) * 512);
            load_lds16(W + (size_t)(n0 + (c >> 2)) * 1024 + k0 + (c & 3) * 8,
                       Bs + (j * 4 + w) * 512);
        }
        __syncthreads();   // drains vmcnt (compiler) -> tile resident
        short8 af[4], bfr[4];
        #pragma unroll
        for (int mi = 0; mi < 4; ++mi)
            af[mi] = *(const short8*)&As[(wm * 64 + mi * 16 + lq) * 32 + lg * 8];
        #pragma unroll
        for (int ni = 0; ni < 4; ++ni)
            bfr[ni] = *(const short8*)&Bs[(wn * 64 + ni * 16 + lq) * 32 + lg * 8];
        #pragma unroll
        for (int mi = 0; mi < 4; ++mi)
            #pragma unroll
            for (int ni = 0; ni < 4; ++ni)
                acc[mi][ni] = __builtin_amdgcn_mfma_f32_16x16x32_bf16(
                    af[mi], bfr[ni], acc[mi][ni], 0, 0, 0);
    }

    // ---------------- epilogue: bf16 scatter via LDS transpose ----------------
    __syncthreads();  // staging reads complete; reuse smem
    const int part = n0 >> 10;                       // 0=Q 1=K 2=V (uniform)
    const int hh = ((n0 + wn * 64) & 1023) >> 6;     // head (uniform per wave)
    const int mrow0 = m0 + wm * 64;
    const int bh = (mrow0 >> 11) * 16 + hh;
    const int tok0 = mrow0 & 2047;
    const float scl = (part == 0) ? 0.125f : 1.0f;

    float bias4[4];
    #pragma unroll
    for (int ni = 0; ni < 4; ++ni)
        bias4[ni] = bias[n0 + wn * 64 + ni * 16 + lq];

    uint16_t* T = smem + w * 4608;                   // [64][72] bf16, wave-private
    if (part < 2) {
        #pragma unroll
        for (int mi = 0; mi < 4; ++mi)
            #pragma unroll
            for (int ni = 0; ni < 4; ++ni)
                #pragma unroll
                for (int r = 0; r < 4; ++r)
                    T[(mi * 16 + lg * 4 + r) * 72 + ni * 16 + lq] =
                        f2bf((acc[mi][ni][r] + bias4[ni]) * scl);
    } else {
        #pragma unroll
        for (int mi = 0; mi < 4; ++mi)
            #pragma unroll
            for (int ni = 0; ni < 4; ++ni)
                #pragma unroll
                for (int r = 0; r < 4; ++r)
                    T[(ni * 16 + lq) * 72 + mi * 16 + lg * 4 + r] =
                        f2bf(acc[mi][ni][r] + bias4[ni]);
    }

    const int a0 = l >> 3, b8 = (l & 7) * 8;
    #pragma unroll
    for (int i = 0; i < 8; ++i) {
        int a = i * 8 + a0;
        short8 u = *(short8*)&T[a * 72 + b8];
        uint16_t* p;
        if (part < 2) {
            uint16_t* dst = (part == 0) ? Qb : Kb;
            p = dst + ((size_t)bh * 2048 + tok0 + a) * 64 + b8;
        } else {
            p = Vt + ((size_t)bh * 64 + a) * 2048 + tok0 + b8;
        }
        *(short8*)p = u;
    }
}

// ======================= MFMA flash attention =======================
// One q-tile (64 rows) per block; 4 waves x 16 q-rows. Longest blocks first.
__global__ __launch_bounds__(256) void attn_mfma(
    const uint16_t* __restrict__ Q, const uint16_t* __restrict__ K,
    const uint16_t* __restrict__ Vt, uint16_t* __restrict__ Y)
{
    const int bh = blockIdx.y;
    const int w = threadIdx.x >> 6;
    const int lane = threadIdx.x & 63;
    const int lq = lane & 15;
    const int lg = lane >> 4;

    __shared__ __align__(16) uint16_t Pl[4][16][72];

    const uint16_t* Kb = K + (size_t)bh * (2048 * 64);
    const uint16_t* Vb = Vt + (size_t)bh * (64 * 2048);
    const int b = bh >> 4, h = bh & 15;

    const int qt = 31 - (int)blockIdx.x;    // biggest workload first
    const int q0 = qt * 64 + w * 16;

    const uint16_t* qbase = Q + ((size_t)bh * 2048 + q0 + lq) * 64 + lg * 8;
    short8 qf0 = *(const short8*)qbase;
    short8 qf1 = *(const short8*)(qbase + 32);

    f32x4 y[4] = {};
    float m[4], lsum[4];
    #pragma unroll
    for (int r = 0; r < 4; ++r) { m[r] = -INFINITY; lsum[r] = 0.f; }

    for (int kt = 0; kt <= qt; ++kt) {
        const int kv0 = kt * 64;
        f32x4 s[4];
        #pragma unroll
        for (int n = 0; n < 4; ++n) {
            const uint16_t* kbase = Kb + (size_t)(kv0 + n * 16 + lq) * 64 + lg * 8;
            short8 kf0 = *(const short8*)kbase;
            short8 kf1 = *(const short8*)(kbase + 32);
            f32x4 z = {};
            z = __builtin_amdgcn_mfma_f32_16x16x32_bf16(qf0, kf0, z, 0, 0, 0);
            s[n] = __builtin_amdgcn_mfma_f32_16x16x32_bf16(qf1, kf1, z, 0, 0, 0);
        }
        if (kt == qt) {
            const int rowb = q0 + lg * 4;
            #pragma unroll
            for (int n = 0; n < 4; ++n) {
                int col = kv0 + n * 16 + lq;
                #pragma unroll
                for (int r = 0; r < 4; ++r)
                    if (col > rowb + r) s[n][r] = -INFINITY;
            }
        }
        float mt[4];
        #pragma unroll
        for (int r = 0; r < 4; ++r)
            mt[r] = fmaxf(fmaxf(s[0][r], s[1][r]), fmaxf(s[2][r], s[3][r]));
        #pragma unroll
        for (int off = 1; off <= 8; off <<= 1)
            #pragma unroll
            for (int r = 0; r < 4; ++r)
                mt[r] = fmaxf(mt[r], __shfl_xor(mt[r], off));
        float sc[4], psum[4];
        #pragma unroll
        for (int r = 0; r < 4; ++r) {
            float mn = fmaxf(m[r], mt[r]);
            sc[r] = __expf(m[r] - mn);
            m[r] = mn;
            psum[r] = 0.f;
        }
        #pragma unroll
        for (int n = 0; n < 4; ++n)
            #pragma unroll
            for (int r = 0; r < 4; ++r) {
                float p = __expf(s[n][r] - m[r]);
                psum[r] += p;
                Pl[w][lg * 4 + r][n * 16 + lq] = f2bf(p);
            }
        #pragma unroll
        for (int off = 1; off <= 8; off <<= 1)
            #pragma unroll
            for (int r = 0; r < 4; ++r)
                psum[r] += __shfl_xor(psum[r], off);
        #pragma unroll
        for (int r = 0; r < 4; ++r) lsum[r] = lsum[r] * sc[r] + psum[r];
        #pragma unroll
        for (int n = 0; n < 4; ++n)
            #pragma unroll
            for (int r = 0; r < 4; ++r)
                y[n][r] *= sc[r];
        short8 pa0 = *(short8*)&Pl[w][lq][lg * 8];
        short8 pa1 = *(short8*)&Pl[w][lq][lg * 8 + 32];
        #pragma unroll
        for (int n = 0; n < 4; ++n) {
            const uint16_t* vbase = Vb + (size_t)(n * 16 + lq) * 2048 + kv0 + lg * 8;
            short8 vf0 = *(const short8*)vbase;
            short8 vf1 = *(const short8*)(vbase + 32);
            y[n] = __builtin_amdgcn_mfma_f32_16x16x32_bf16(pa0, vf0, y[n], 0, 0, 0);
            y[n] = __builtin_amdgcn_mfma_f32_16x16x32_bf16(pa1, vf1, y[n], 0, 0, 0);
        }
    }
    #pragma unroll
    for (int r = 0; r < 4; ++r) {
        float inv = 1.0f / lsum[r];
        int token = b * 2048 + q0 + lg * 4 + r;
        uint16_t* yrow = Y + (size_t)token * 1024 + h * 64;
        #pragma unroll
        for (int n = 0; n < 4; ++n)
            yrow[n * 16 + lq] = f2bf(y[n][r] * inv);
    }
}

// ======================= output projection (MFMA, fp32 out) =======================
// out[4096,1024] = Y(bf16) @ Wo(bf16)^T + bo
__global__ __launch_bounds__(256) void gemm_proj(
    const uint16_t* __restrict__ Yin, const uint16_t* __restrict__ W,
    const float* __restrict__ bias, float* __restrict__ out)
{
    __shared__ __align__(16) uint16_t smem[8192];   // 2 x [128][32]
    uint16_t* As = smem;
    uint16_t* Bs = smem + 4096;

    const int tid = threadIdx.x;
    const int w = tid >> 6, l = tid & 63;
    const int lq = l & 15, lg = l >> 4;
    const int wm = w >> 1, wn = w & 1;
    const int m0 = blockIdx.y * 128;
    const int n0 = blockIdx.x * 128;

    f32x4 acc[4][4] = {};

    for (int k0 = 0; k0 < 1024; k0 += 32) {
        __syncthreads();
        #pragma unroll
        for (int j = 0; j < 2; ++j) {
            const int c = (j * 4 + w) * 64 + l;
            load_lds16(Yin + (size_t)(m0 + (c >> 2)) * 1024 + k0 + (c & 3) * 8,
                       As + (j * 4 + w) * 512);
            load_lds16(W + (size_t)(n0 + (c >> 2)) * 1024 + k0 + (c & 3) * 8,
                       Bs + (j * 4 + w) * 512);
        }
        __syncthreads();
        short8 af[4], bfr[4];
        #pragma unroll
        for (int mi = 0; mi < 4; ++mi)
            af[mi] = *(const short8*)&As[(wm * 64 + mi * 16 + lq) * 32 + lg * 8];
        #pragma unroll
        for (int ni = 0; ni < 4; ++ni)
            bfr[ni] = *(const short8*)&Bs[(wn * 64 + ni * 16 + lq) * 32 + lg * 8];
        #pragma unroll
        for (int mi = 0; mi < 4; ++mi)
            #pragma unroll
            for (int ni = 0; ni < 4; ++ni)
                acc[mi][ni] = __builtin_amdgcn_mfma_f32_16x16x32_bf16(
                    af[mi], bfr[ni], acc[mi][ni], 0, 0, 0);
    }

    // epilogue: direct fp32 stores from C-fragment layout
    const int mrow0 = m0 + wm * 64;
    const int ncol0 = n0 + wn * 64;
    float bias4[4];
    #pragma unroll
    for (int ni = 0; ni < 4; ++ni)
        bias4[ni] = bias[ncol0 + ni * 16 + lq];

    #pragma unroll
    for (int mi = 0; mi < 4; ++mi)
        #pragma unroll
        for (int r = 0; r < 4; ++r) {
            const size_t rowoff = (size_t)(mrow0 + mi * 16 + lg * 4 + r) * 1024;
            #pragma unroll
            for (int ni = 0; ni < 4; ++ni)
                out[rowoff + ncol0 + ni * 16 + lq] = acc[mi][ni][r] + bias4[ni];
        }
}

// ======================= launcher =======================

extern "C" void kernel_launch(void* const* d_in, const int* in_sizes, int n_in,
                              void* d_out, int out_size, void* d_ws, size_t ws_size,
                              hipStream_t stream) {
    const float* x    = (const float*)d_in[0];
    // d_in[1] (causal mask) applied structurally.
    const float* Wqkv = (const float*)d_in[2];
    const float* bqkv = (const float*)d_in[3];
    const float* Wo   = (const float*)d_in[4];
    const float* bo   = (const float*)d_in[5];

    const int XE  = 4096 * 1024;   // 4,194,304
    const int WQE = 3072 * 1024;   // 3,145,728
    const int WOE = 1024 * 1024;   // 1,048,576
    const size_t QK = (size_t)BB * HH * NN * SS;  // 4,194,304

    uint16_t* Xb  = (uint16_t*)d_ws;
    uint16_t* Wqb = Xb + XE;
    uint16_t* Wob = Wqb + WQE;
    uint16_t* Qb  = Wob + WOE;
    uint16_t* Kb  = Qb + QK;
    uint16_t* Vt  = Kb + QK;
    uint16_t* Yb  = Vt + QK;

    cvt_bf16<<<XE / 8 / 256, 256, 0, stream>>>(x, Xb, XE);
    cvt_bf16<<<WQE / 8 / 256, 256, 0, stream>>>(Wqkv, Wqb, WQE);
    cvt_bf16<<<WOE / 8 / 256, 256, 0, stream>>>(Wo, Wob, WOE);
    gemm_qkv<<<dim3(24, 32), 256, 0, stream>>>(Xb, Wqb, bqkv, Qb, Kb, Vt);
    attn_mfma<<<dim3(32, 32), 256, 0, stream>>>(Qb, Kb, Vt, Yb);
    gemm_proj<<<dim3(8, 32), 256, 0, stream>>>(Yb, Wob, bo, (float*)d_out);
}

// Round 7
// 204.447 us; speedup vs baseline: 21.9226x; 1.6172x over previous
//
#include <hip/hip_runtime.h>
#include <hip/hip_bf16.h>
#include <stdint.h>

// Problem constants: B=2, N=2048, D=1024, H=16, head dim s=64.
// Global I/O fp32; internal X/W/Q/K/V/Y intermediates bf16 in d_ws.
#define BB 2
#define NN 2048
#define DD 1024
#define HH 16
#define SS 64

typedef short short8 __attribute__((ext_vector_type(8)));
typedef float f32x4 __attribute__((ext_vector_type(4)));

__device__ __forceinline__ float bf2f(uint16_t u) {
    return __uint_as_float(((uint32_t)u) << 16);
}
__device__ __forceinline__ uint16_t f2bf(float f) {
    uint32_t u = __float_as_uint(f);
    return (uint16_t)((u + 0x7FFFu + ((u >> 16) & 1u)) >> 16);  // RNE
}
__device__ __forceinline__ short8 cvt8(float4 a, float4 b) {
    short8 s;
    s[0] = (short)f2bf(a.x); s[1] = (short)f2bf(a.y);
    s[2] = (short)f2bf(a.z); s[3] = (short)f2bf(a.w);
    s[4] = (short)f2bf(b.x); s[5] = (short)f2bf(b.y);
    s[6] = (short)f2bf(b.z); s[7] = (short)f2bf(b.w);
    return s;
}

__device__ __forceinline__ void load_lds16(const uint16_t* g, uint16_t* l) {
    __builtin_amdgcn_global_load_lds(
        (const __attribute__((address_space(1))) void*)g,
        (__attribute__((address_space(3))) void*)l, 16, 0, 0);
}

// ======================= fp32 -> bf16 bulk convert =======================
__global__ __launch_bounds__(256) void cvt_bf16(
    const float* __restrict__ src, uint16_t* __restrict__ dst, int n)
{
    int i = (blockIdx.x * 256 + threadIdx.x) * 8;
    if (i >= n) return;
    float4 a = *(const float4*)(src + i);
    float4 b = *(const float4*)(src + i + 4);
    *(short8*)(dst + i) = cvt8(a, b);
}

// ======================= QKV projection (MFMA, bf16 in) =======================
// C[4096,3072] = X[4096,1024] @ Wqkv[3072,1024]^T + bqkv
// -> Q bf16 (x0.125) [bh][2048][64], K bf16 [bh][2048][64], V^T bf16 [bh][64][2048]
__global__ __launch_bounds__(256) void gemm_qkv(
    const uint16_t* __restrict__ X, const uint16_t* __restrict__ W,
    const float* __restrict__ bias,
    uint16_t* __restrict__ Qb, uint16_t* __restrict__ Kb, uint16_t* __restrict__ Vt)
{
    __shared__ __align__(16) uint16_t smem[18432];   // 36,864 B
    uint16_t* As = smem;          // [128][32] linear (gload_lds requires)
    uint16_t* Bs = smem + 4096;   // [128][32]

    const int tid = threadIdx.x;
    const int w = tid >> 6, l = tid & 63;
    const int lq = l & 15, lg = l >> 4;
    const int wm = w >> 1, wn = w & 1;
    const int m0 = blockIdx.y * 128;
    const int n0 = blockIdx.x * 128;

    f32x4 acc[4][4] = {};

    for (int k0 = 0; k0 < 1024; k0 += 32) {
        __syncthreads();
        #pragma unroll
        for (int j = 0; j < 2; ++j) {
            const int c = (j * 4 + w) * 64 + l;   // lane's global row/col chunk
            load_lds16(X + (size_t)(m0 + (c >> 2)) * 1024 + k0 + (c & 3) * 8,
                       As + (j * 4 + w) * 512);
            load_lds16(W + (size_t)(n0 + (c >> 2)) * 1024 + k0 + (c & 3) * 8,
                       Bs + (j * 4 + w) * 512);
        }
        __syncthreads();
        short8 af[4], bfr[4];
        #pragma unroll
        for (int mi = 0; mi < 4; ++mi)
            af[mi] = *(const short8*)&As[(wm * 64 + mi * 16 + lq) * 32 + lg * 8];
        #pragma unroll
        for (int ni = 0; ni < 4; ++ni)
            bfr[ni] = *(const short8*)&Bs[(wn * 64 + ni * 16 + lq) * 32 + lg * 8];
        #pragma unroll
        for (int mi = 0; mi < 4; ++mi)
            #pragma unroll
            for (int ni = 0; ni < 4; ++ni)
                acc[mi][ni] = __builtin_amdgcn_mfma_f32_16x16x32_bf16(
                    af[mi], bfr[ni], acc[mi][ni], 0, 0, 0);
    }

    // ---------------- epilogue: bf16 scatter via LDS transpose ----------------
    __syncthreads();  // staging reads complete; reuse smem
    const int part = n0 >> 10;                       // 0=Q 1=K 2=V (uniform)
    const int hh = ((n0 + wn * 64) & 1023) >> 6;     // head (uniform per wave)
    const int mrow0 = m0 + wm * 64;
    const int bh = (mrow0 >> 11) * 16 + hh;
    const int tok0 = mrow0 & 2047;
    const float scl = (part == 0) ? 0.125f : 1.0f;

    float bias4[4];
    #pragma unroll
    for (int ni = 0; ni < 4; ++ni)
        bias4[ni] = bias[n0 + wn * 64 + ni * 16 + lq];

    uint16_t* T = smem + w * 4608;                   // [64][72] bf16, wave-private
    if (part < 2) {
        #pragma unroll
        for (int mi = 0; mi < 4; ++mi)
            #pragma unroll
            for (int ni = 0; ni < 4; ++ni)
                #pragma unroll
                for (int r = 0; r < 4; ++r)
                    T[(mi * 16 + lg * 4 + r) * 72 + ni * 16 + lq] =
                        f2bf((acc[mi][ni][r] + bias4[ni]) * scl);
    } else {
        #pragma unroll
        for (int mi = 0; mi < 4; ++mi)
            #pragma unroll
            for (int ni = 0; ni < 4; ++ni)
                #pragma unroll
                for (int r = 0; r < 4; ++r)
                    T[(ni * 16 + lq) * 72 + mi * 16 + lg * 4 + r] =
                        f2bf(acc[mi][ni][r] + bias4[ni]);
    }

    const int a0 = l >> 3, b8 = (l & 7) * 8;
    #pragma unroll
    for (int i = 0; i < 8; ++i) {
        int a = i * 8 + a0;
        short8 u = *(short8*)&T[a * 72 + b8];
        uint16_t* p;
        if (part < 2) {
            uint16_t* dst = (part == 0) ? Qb : Kb;
            p = dst + ((size_t)bh * 2048 + tok0 + a) * 64 + b8;
        } else {
            p = Vt + ((size_t)bh * 64 + a) * 2048 + tok0 + b8;
        }
        *(short8*)p = u;
    }
}

// ======================= MFMA flash attention (pipelined) =======================
// 1D grid 512: id%8 -> XCD-affine bh group (K/V L2 locality); in-block pairing
// {x, 31-x} -> uniform 33 kv-iterations. K regs double-buffered; V prefetched.
__device__ __forceinline__ void loadKf(const uint16_t* Kb, int kv0, int lq, int lg,
                                       short8 (&d)[8]) {
    #pragma unroll
    for (int n = 0; n < 4; ++n) {
        const uint16_t* kb = Kb + (size_t)(kv0 + n * 16 + lq) * 64 + lg * 8;
        d[2 * n]     = *(const short8*)kb;
        d[2 * n + 1] = *(const short8*)(kb + 32);
    }
}
__device__ __forceinline__ void loadVf(const uint16_t* Vb, int kv0, int lq, int lg,
                                       short8 (&d)[8]) {
    #pragma unroll
    for (int n = 0; n < 4; ++n) {
        const uint16_t* vb = Vb + (size_t)(n * 16 + lq) * 2048 + kv0 + lg * 8;
        d[2 * n]     = *(const short8*)vb;
        d[2 * n + 1] = *(const short8*)(vb + 32);
    }
}

__global__ __launch_bounds__(256) void attn_mfma(
    const uint16_t* __restrict__ Q, const uint16_t* __restrict__ K,
    const uint16_t* __restrict__ Vt, uint16_t* __restrict__ Y)
{
    const int id = blockIdx.x;
    const int bh = (id & 7) + (((id >> 3) & 3) << 3);   // id%8 stable per bh
    const int xpair = id >> 5;                          // 0..15
    const int w = threadIdx.x >> 6;
    const int lane = threadIdx.x & 63;
    const int lq = lane & 15;
    const int lg = lane >> 4;

    __shared__ __align__(16) uint16_t Pl[4][16][72];

    const uint16_t* Kb = K + (size_t)bh * (2048 * 64);
    const uint16_t* Vb = Vt + (size_t)bh * (64 * 2048);
    const int b = bh >> 4, h = bh & 15;

    for (int half = 0; half < 2; ++half) {
        const int qt = half ? (31 - xpair) : xpair;
        const int q0 = qt * 64 + w * 16;

        const uint16_t* qbase = Q + ((size_t)bh * 2048 + q0 + lq) * 64 + lg * 8;
        short8 qf0 = *(const short8*)qbase;
        short8 qf1 = *(const short8*)(qbase + 32);

        f32x4 y[4] = {};
        float m[4], lsum[4];
        #pragma unroll
        for (int r = 0; r < 4; ++r) { m[r] = -INFINITY; lsum[r] = 0.f; }

        short8 kfA[8], kfB[8], vv[8];
        loadKf(Kb, 0, lq, lg, kfA);

        auto step = [&](short8 (&kf)[8], short8 (&kn)[8], int kt) {
            const int kv0 = kt * 64;
            // issue V(t) and K(t+1) loads first; QK uses in-register kf
            loadVf(Vb, kv0, lq, lg, vv);
            if (kt < qt) loadKf(Kb, kv0 + 64, lq, lg, kn);

            f32x4 s[4];
            #pragma unroll
            for (int n = 0; n < 4; ++n) {
                f32x4 z = {};
                z = __builtin_amdgcn_mfma_f32_16x16x32_bf16(qf0, kf[2 * n], z, 0, 0, 0);
                s[n] = __builtin_amdgcn_mfma_f32_16x16x32_bf16(qf1, kf[2 * n + 1], z, 0, 0, 0);
            }
            if (kt == qt) {
                const int rowb = q0 + lg * 4;
                #pragma unroll
                for (int n = 0; n < 4; ++n) {
                    int col = kv0 + n * 16 + lq;
                    #pragma unroll
                    for (int r = 0; r < 4; ++r)
                        if (col > rowb + r) s[n][r] = -INFINITY;
                }
            }
            float mt[4];
            #pragma unroll
            for (int r = 0; r < 4; ++r)
                mt[r] = fmaxf(fmaxf(s[0][r], s[1][r]), fmaxf(s[2][r], s[3][r]));
            #pragma unroll
            for (int off = 1; off <= 8; off <<= 1)
                #pragma unroll
                for (int r = 0; r < 4; ++r)
                    mt[r] = fmaxf(mt[r], __shfl_xor(mt[r], off));
            float sc[4], psum[4];
            #pragma unroll
            for (int r = 0; r < 4; ++r) {
                float mn = fmaxf(m[r], mt[r]);
                sc[r] = __expf(m[r] - mn);
                m[r] = mn;
                psum[r] = 0.f;
            }
            #pragma unroll
            for (int n = 0; n < 4; ++n)
                #pragma unroll
                for (int r = 0; r < 4; ++r) {
                    float p = __expf(s[n][r] - m[r]);
                    psum[r] += p;
                    Pl[w][lg * 4 + r][n * 16 + lq] = f2bf(p);
                }
            #pragma unroll
            for (int off = 1; off <= 8; off <<= 1)
                #pragma unroll
                for (int r = 0; r < 4; ++r)
                    psum[r] += __shfl_xor(psum[r], off);
            #pragma unroll
            for (int r = 0; r < 4; ++r) lsum[r] = lsum[r] * sc[r] + psum[r];
            #pragma unroll
            for (int n = 0; n < 4; ++n)
                #pragma unroll
                for (int r = 0; r < 4; ++r)
                    y[n][r] *= sc[r];
            short8 pa0 = *(short8*)&Pl[w][lq][lg * 8];
            short8 pa1 = *(short8*)&Pl[w][lq][lg * 8 + 32];
            #pragma unroll
            for (int n = 0; n < 4; ++n) {
                y[n] = __builtin_amdgcn_mfma_f32_16x16x32_bf16(pa0, vv[2 * n], y[n], 0, 0, 0);
                y[n] = __builtin_amdgcn_mfma_f32_16x16x32_bf16(pa1, vv[2 * n + 1], y[n], 0, 0, 0);
            }
        };

        int kt = 0;
        while (true) {
            step(kfA, kfB, kt);
            if (kt == qt) break;
            ++kt;
            step(kfB, kfA, kt);
            if (kt == qt) break;
            ++kt;
        }

        #pragma unroll
        for (int r = 0; r < 4; ++r) {
            float inv = 1.0f / lsum[r];
            int token = b * 2048 + q0 + lg * 4 + r;
            uint16_t* yrow = Y + (size_t)token * 1024 + h * 64;
            #pragma unroll
            for (int n = 0; n < 4; ++n)
                yrow[n * 16 + lq] = f2bf(y[n][r] * inv);
        }
    }
}

// ======================= output projection (MFMA, fp32 out) =======================
// out[4096,1024] = Y(bf16) @ Wo(bf16)^T + bo
__global__ __launch_bounds__(256) void gemm_proj(
    const uint16_t* __restrict__ Yin, const uint16_t* __restrict__ W,
    const float* __restrict__ bias, float* __restrict__ out)
{
    __shared__ __align__(16) uint16_t smem[8192];   // 2 x [128][32]
    uint16_t* As = smem;
    uint16_t* Bs = smem + 4096;

    const int tid = threadIdx.x;
    const int w = tid >> 6, l = tid & 63;
    const int lq = l & 15, lg = l >> 4;
    const int wm = w >> 1, wn = w & 1;
    const int m0 = blockIdx.y * 128;
    const int n0 = blockIdx.x * 128;

    f32x4 acc[4][4] = {};

    for (int k0 = 0; k0 < 1024; k0 += 32) {
        __syncthreads();
        #pragma unroll
        for (int j = 0; j < 2; ++j) {
            const int c = (j * 4 + w) * 64 + l;
            load_lds16(Yin + (size_t)(m0 + (c >> 2)) * 1024 + k0 + (c & 3) * 8,
                       As + (j * 4 + w) * 512);
            load_lds16(W + (size_t)(n0 + (c >> 2)) * 1024 + k0 + (c & 3) * 8,
                       Bs + (j * 4 + w) * 512);
        }
        __syncthreads();
        short8 af[4], bfr[4];
        #pragma unroll
        for (int mi = 0; mi < 4; ++mi)
            af[mi] = *(const short8*)&As[(wm * 64 + mi * 16 + lq) * 32 + lg * 8];
        #pragma unroll
        for (int ni = 0; ni < 4; ++ni)
            bfr[ni] = *(const short8*)&Bs[(wn * 64 + ni * 16 + lq) * 32 + lg * 8];
        #pragma unroll
        for (int mi = 0; mi < 4; ++mi)
            #pragma unroll
            for (int ni = 0; ni < 4; ++ni)
                acc[mi][ni] = __builtin_amdgcn_mfma_f32_16x16x32_bf16(
                    af[mi], bfr[ni], acc[mi][ni], 0, 0, 0);
    }

    // epilogue: direct fp32 stores from C-fragment layout
    const int mrow0 = m0 + wm * 64;
    const int ncol0 = n0 + wn * 64;
    float bias4[4];
    #pragma unroll
    for (int ni = 0; ni < 4; ++ni)
        bias4[ni] = bias[ncol0 + ni * 16 + lq];

    #pragma unroll
    for (int mi = 0; mi < 4; ++mi)
        #pragma unroll
        for (int r = 0; r < 4; ++r) {
            const size_t rowoff = (size_t)(mrow0 + mi * 16 + lg * 4 + r) * 1024;
            #pragma unroll
            for (int ni = 0; ni < 4; ++ni)
                out[rowoff + ncol0 + ni * 16 + lq] = acc[mi][ni][r] + bias4[ni];
        }
}

// ======================= launcher =======================

extern "C" void kernel_launch(void* const* d_in, const int* in_sizes, int n_in,
                              void* d_out, int out_size, void* d_ws, size_t ws_size,
                              hipStream_t stream) {
    const float* x    = (const float*)d_in[0];
    // d_in[1] (causal mask) applied structurally.
    const float* Wqkv = (const float*)d_in[2];
    const float* bqkv = (const float*)d_in[3];
    const float* Wo   = (const float*)d_in[4];
    const float* bo   = (const float*)d_in[5];

    const int XE  = 4096 * 1024;   // 4,194,304
    const int WQE = 3072 * 1024;   // 3,145,728
    const int WOE = 1024 * 1024;   // 1,048,576
    const size_t QK = (size_t)BB * HH * NN * SS;  // 4,194,304

    uint16_t* Xb  = (uint16_t*)d_ws;
    uint16_t* Wqb = Xb + XE;
    uint16_t* Wob = Wqb + WQE;
    uint16_t* Qb  = Wob + WOE;
    uint16_t* Kb  = Qb + QK;
    uint16_t* Vt  = Kb + QK;
    uint16_t* Yb  = Vt + QK;

    cvt_bf16<<<XE / 8 / 256, 256, 0, stream>>>(x, Xb, XE);
    cvt_bf16<<<WQE / 8 / 256, 256, 0, stream>>>(Wqkv, Wqb, WQE);
    cvt_bf16<<<WOE / 8 / 256, 256, 0, stream>>>(Wo, Wob, WOE);
    gemm_qkv<<<dim3(24, 32), 256, 0, stream>>>(Xb, Wqb, bqkv, Qb, Kb, Vt);
    attn_mfma<<<512, 256, 0, stream>>>(Qb, Kb, Vt, Yb);
    gemm_proj<<<dim3(8, 32), 256, 0, stream>>>(Yb, Wob, bo, (float*)d_out);
}